// Round 14
// baseline (2909.013 us; speedup 1.0000x reference)
//
#include <hip/hip_runtime.h>

#define SEQ  512
#define IDIM 256
#define HD   1024
#define BT   256
#define NCLS 10

#define GR    8         // row groups (128 rows each)
#define GB    16        // batch groups (16 cols each)
#define NWG   (GR*GB)   // 128 WGs
#define TPB   512       // 8 waves
#define KKH   32        // h kk-blocks (K=1024)
#define KKX   8         // x kk-blocks (K=256)
#define NSLOT 4         // h slot ring depth
#define SENT  0x7F80    // bf16 +inf: impossible as tanh output

typedef __attribute__((ext_vector_type(8))) short short8;
typedef __attribute__((ext_vector_type(4))) float f32x4;
typedef __attribute__((ext_vector_type(4))) unsigned short us4;
typedef __attribute__((ext_vector_type(4))) int i32x4;

// h slot ring, B-fragment order per col-group; h_t in slot t%4; sentinel
// self-validating data (R12-proven). NEW: publishes are done by ONE wave
// per WG from an LDS gather, so compute waves carry NO global stores --
// no store-ack ever drains on the critical path.
__device__ unsigned short g_h[NSLOT][GB][KKH*64*8];
__device__ float g_hfinal[BT][HD];
__device__ unsigned g_bar, g_done_all;

__device__ __forceinline__ unsigned short f2bf(float f){
    unsigned int u = __builtin_bit_cast(unsigned int, f);
    u += 0x7fffu + ((u >> 16) & 1u);        // round-to-nearest-even
    return (unsigned short)(u >> 16);
}
__device__ __forceinline__ float fast_tanh(float v){
    float e = __expf(2.0f * v);             // exact: tanh = 1 - 2/(e^2v+1)
    return 1.0f - 2.0f / (e + 1.0f);
}
__device__ __forceinline__ void sys_st64(unsigned short* p, unsigned long long v){
    __hip_atomic_store((unsigned long long*)p, v, __ATOMIC_RELAXED, __HIP_MEMORY_SCOPE_SYSTEM);
}
// raw workgroup barrier: LDS-ordered only, NO vmcnt drain (the whole point)
__device__ __forceinline__ void bar_lgkm(){
    asm volatile("s_waitcnt lgkmcnt(0)" ::: "memory");
    __builtin_amdgcn_sched_barrier(0);
    __builtin_amdgcn_s_barrier();
    __builtin_amdgcn_sched_barrier(0);
}

__global__
__attribute__((amdgpu_flat_work_group_size(TPB, TPB), amdgpu_waves_per_eu(2, 2)))
void rnn_main(
    const float* __restrict__ x, const float* __restrict__ w_hx,
    const float* __restrict__ w_hh, const float* __restrict__ b_h)
{
    __shared__ unsigned short sX[8*KKX*64*8];   // 64 KB W_hx A-frags
    __shared__ unsigned short sB[KKH*64*8];     // 32 KB h slab
    __shared__ unsigned long long hbuf[512];    // 4 KB: WG's h output, frag order

    const int tid = threadIdx.x;
    const int wg  = blockIdx.x;
    const int gbg = wg & (GB-1);
    const int gr  = wg >> 4;
    const int r0  = gr * 128;
    const int b0  = gbg * 16;
    const int l   = tid & 63;
    const int w   = tid >> 6;
    const int rw  = r0 + w*16;
    const int row = rw + (l & 15);
    const int ko  = (l >> 4) << 3;

    // ---- W_hh -> wa, pinned (AGPR spill = on-chip; R10/R12-proven)
    i32x4 wa[KKH];
    #pragma unroll
    for (int kk = 0; kk < KKH; ++kk){
        f32x4 v0 = *(const f32x4*)(w_hh + (size_t)row*HD + kk*32 + ko);
        f32x4 v1 = *(const f32x4*)(w_hh + (size_t)row*HD + kk*32 + ko + 4);
        us4 lo = { f2bf(v0[0]), f2bf(v0[1]), f2bf(v0[2]), f2bf(v0[3]) };
        us4 hi = { f2bf(v1[0]), f2bf(v1[1]), f2bf(v1[2]), f2bf(v1[3]) };
        unsigned long long a = __builtin_bit_cast(unsigned long long, lo);
        unsigned long long b = __builtin_bit_cast(unsigned long long, hi);
        i32x4 q;
        q[0] = (int)(a & 0xffffffffu); q[1] = (int)(a >> 32);
        q[2] = (int)(b & 0xffffffffu); q[3] = (int)(b >> 32);
        wa[kk] = q;
    }
    #pragma unroll
    for (int kk = 0; kk < KKH; ++kk)
        asm volatile("" : "+v"(wa[kk]));

    // ---- W_hx A-frags -> LDS
    #pragma unroll
    for (int xk = 0; xk < KKX; ++xk){
        f32x4 v0 = *(const f32x4*)(w_hx + (size_t)row*IDIM + xk*32 + ko);
        f32x4 v1 = *(const f32x4*)(w_hx + (size_t)row*IDIM + xk*32 + ko + 4);
        short8 a;
        a[0]=(short)f2bf(v0[0]); a[1]=(short)f2bf(v0[1]);
        a[2]=(short)f2bf(v0[2]); a[3]=(short)f2bf(v0[3]);
        a[4]=(short)f2bf(v1[0]); a[5]=(short)f2bf(v1[1]);
        a[6]=(short)f2bf(v1[2]); a[7]=(short)f2bf(v1[3]);
        *(short8*)&sX[(size_t)((w*KKX + xk)*64 + l)*8] = a;
    }

    const f32x4 bias = *(const f32x4*)(b_h + rw + ((l >> 4) << 2));
    const float* xlane = x + (size_t)(b0 + (l & 15))*(SEQ*IDIM) + ko;

    const int rloc  = w*16 + ((l >> 4) << 2);
    const int kkd   = gr*4 + (rloc >> 5);
    const int lnp   = (l & 15) | (((rloc >> 3) & 3) << 4);
    const int sboff = kkd*512 + lnp*8 + (rloc & 7);       // slab/global index
    const int loc   = sboff - gr*4*512;                   // 0..2047, mult of 4
    us4 hw_prev = {0, 0, 0, 0};

    // ---- init ring: slot 0 = zeros (h_0), slots 1..3 = sentinel
    sys_st64(&g_h[0][gbg][sboff], 0ull);
    {
        int sv = SENT;
        #pragma unroll
        for (int s = 1; s < NSLOT; ++s){
            unsigned short* p = &g_h[s][gbg][sboff];
            asm volatile("global_store_short %0, %1, off sc0 sc1" :: "v"(p), "v"(sv) : "memory");
        }
    }
    asm volatile("s_waitcnt vmcnt(0)" ::: "memory");
    __syncthreads();
    if (tid == 0){
        __hip_atomic_fetch_add(&g_bar, 1u, __ATOMIC_ACQ_REL, __HIP_MEMORY_SCOPE_SYSTEM);
        int guard = 0;
        while (__hip_atomic_load(&g_bar, __ATOMIC_ACQUIRE, __HIP_MEMORY_SCOPE_SYSTEM) < NWG
               && ++guard < (1 << 22)) { }
    }
    __syncthreads();

    auto xpart = [&](const float* xp) -> f32x4 {
        f32x4 a = bias;
        #pragma unroll
        for (int xk = 0; xk < KKX; ++xk){
            f32x4 v0 = *(const f32x4*)(xp + xk*32);
            f32x4 v1 = *(const f32x4*)(xp + xk*32 + 4);
            short8 bx;
            bx[0]=(short)f2bf(v0[0]); bx[1]=(short)f2bf(v0[1]);
            bx[2]=(short)f2bf(v0[2]); bx[3]=(short)f2bf(v0[3]);
            bx[4]=(short)f2bf(v1[0]); bx[5]=(short)f2bf(v1[1]);
            bx[6]=(short)f2bf(v1[2]); bx[7]=(short)f2bf(v1[3]);
            short8 aw = *(const short8*)&sX[(size_t)((w*KKX + xk)*64 + l)*8];
            a = __builtin_amdgcn_mfma_f32_16x16x32_bf16(aw, bx, a, 0, 0, 0);
        }
        return a;
    };
    f32x4 accX = xpart(xlane);

    for (int t = 0; t < SEQ; ++t){
        const int slot = t & 3;
        const int ns   = (t + 1) & 3;
        const int ps   = (t + 3) & 3;

        // ================= phase A: stage slot t (loads only) =============
        *(us4*)&sB[sboff] = hw_prev;              // own word from registers
        if (w != gr){
            const unsigned short* base = &g_h[slot][gbg][(size_t)(w*4)*512 + l*8];
            i32x4 v0, v1, v2, v3;
            int guard = 0;
            for (;;){
                asm volatile(
                    "global_load_dwordx4 %0, %4, off sc0 sc1\n\t"
                    "global_load_dwordx4 %1, %4, off offset:1024 sc0 sc1\n\t"
                    "global_load_dwordx4 %2, %4, off offset:2048 sc0 sc1\n\t"
                    "global_load_dwordx4 %3, %4, off offset:3072 sc0 sc1"
                    : "=&v"(v0), "=&v"(v1), "=&v"(v2), "=&v"(v3)
                    : "v"(base));
                asm volatile("s_waitcnt vmcnt(0)" ::: "memory");
                bool ok = ((v0[0] & 0xFFFF) != SENT) && ((v0[2] & 0xFFFF) != SENT)
                       && ((v1[0] & 0xFFFF) != SENT) && ((v1[2] & 0xFFFF) != SENT)
                       && ((v2[0] & 0xFFFF) != SENT) && ((v2[2] & 0xFFFF) != SENT)
                       && ((v3[0] & 0xFFFF) != SENT) && ((v3[2] & 0xFFFF) != SENT);
                if (__all(ok)) break;
                if (++guard > (1 << 18)) break;   // hang safety
                __builtin_amdgcn_s_sleep(1);
            }
            *(i32x4*)&sB[(size_t)(w*4+0)*512 + l*8] = v0;
            *(i32x4*)&sB[(size_t)(w*4+1)*512 + l*8] = v1;
            *(i32x4*)&sB[(size_t)(w*4+2)*512 + l*8] = v2;
            *(i32x4*)&sB[(size_t)(w*4+3)*512 + l*8] = v3;
        }
        bar_lgkm();                               // [A] no vmcnt drain

        // ================= phase B: compute ===============================
        f32x4 acc = accX;
        #pragma unroll
        for (int kk = 0; kk < KKH; ++kk){
            short8 b = *(const short8*)&sB[(size_t)(kk*64 + l)*8];
            acc = __builtin_amdgcn_mfma_f32_16x16x32_bf16(
                      __builtin_bit_cast(short8, wa[kk]), b, acc, 0, 0, 0);
        }
        float h0 = fast_tanh(acc[0]);
        float h1 = fast_tanh(acc[1]);
        float h2 = fast_tanh(acc[2]);
        float h3 = fast_tanh(acc[3]);

        if (t < SEQ-1){
            us4 hw = { f2bf(h0), f2bf(h1), f2bf(h2), f2bf(h3) };
            hbuf[loc >> 2] = __builtin_bit_cast(unsigned long long, hw);
            hw_prev = hw;
        } else {
            f32x4 hf = {h0, h1, h2, h3};
            *(f32x4*)&g_hfinal[b0 + (l & 15)][r0 + rloc] = hf;
        }
        bar_lgkm();                               // [B] hbuf visible WG-wide

        // ====== phase C: wave gr publishes (its vmcnt only); all xpart =====
        if (w == gr && t < SEQ-1){
            // slot-reuse ordering: stores from step t-2 must be retired;
            // vmcnt(8) allows last step's 8 to remain in flight.
            asm volatile("s_waitcnt vmcnt(8)" ::: "memory");
            i32x4 d0 = *(i32x4*)&hbuf[(size_t)l*8 + 0];
            i32x4 d1 = *(i32x4*)&hbuf[(size_t)l*8 + 2];
            i32x4 d2 = *(i32x4*)&hbuf[(size_t)l*8 + 4];
            i32x4 d3 = *(i32x4*)&hbuf[(size_t)l*8 + 6];
            unsigned short* dd = &g_h[ns][gbg][(size_t)gr*2048 + l*32];
            asm volatile(
                "global_store_dwordx4 %0, %1, off sc0 sc1\n\t"
                "global_store_dwordx4 %0, %2, off offset:16 sc0 sc1\n\t"
                "global_store_dwordx4 %0, %3, off offset:32 sc0 sc1\n\t"
                "global_store_dwordx4 %0, %4, off offset:48 sc0 sc1"
                :: "v"(dd), "v"(d0), "v"(d1), "v"(d2), "v"(d3) : "memory");
            i32x4 sv = { SENT, 0, SENT, 0 };      // sentinel splat pattern
            unsigned short* ds = &g_h[ps][gbg][(size_t)gr*2048 + l*32];
            asm volatile(
                "global_store_dwordx4 %0, %1, off sc0 sc1\n\t"
                "global_store_dwordx4 %0, %1, off offset:16 sc0 sc1\n\t"
                "global_store_dwordx4 %0, %1, off offset:32 sc0 sc1\n\t"
                "global_store_dwordx4 %0, %1, off offset:48 sc0 sc1"
                :: "v"(ds), "v"(sv) : "memory");
        }
        if (t < SEQ-1)
            accX = xpart(xlane + (size_t)(t+1)*IDIM);
    }

    // ---- epilogue: full drain, then last WG resets counters for replay
    __syncthreads();
    if (tid == 0){
        unsigned old = __hip_atomic_fetch_add(&g_done_all, 1u,
                           __ATOMIC_ACQ_REL, __HIP_MEMORY_SCOPE_SYSTEM);
        if (old == NWG - 1){
            __hip_atomic_store(&g_bar,      0u, __ATOMIC_RELAXED, __HIP_MEMORY_SCOPE_SYSTEM);
            __hip_atomic_store(&g_done_all, 0u, __ATOMIC_RELAXED, __HIP_MEMORY_SCOPE_SYSTEM);
        }
    }
}

// p = w_ph @ h_final + b_p ; out[b][c]
__global__ __launch_bounds__(256, 1) void proj_kernel(
    const float* __restrict__ w_ph, const float* __restrict__ b_p, float* __restrict__ out)
{
    const int b   = blockIdx.x;
    const int tid = threadIdx.x;
    const int l   = tid & 63;
    const int wv  = tid >> 6;
    __shared__ float red[4];
    f32x4 hv = *(const f32x4*)(&g_hfinal[b][0] + tid*4);
    for (int c = 0; c < NCLS; ++c){
        f32x4 wvv = *(const f32x4*)(w_ph + c*HD + tid*4);
        float s = hv[0]*wvv[0] + hv[1]*wvv[1] + hv[2]*wvv[2] + hv[3]*wvv[3];
        #pragma unroll
        for (int off = 32; off; off >>= 1) s += __shfl_down(s, off, 64);
        if (l == 0) red[wv] = s;
        __syncthreads();
        if (tid == 0) out[b*NCLS + c] = red[0] + red[1] + red[2] + red[3] + b_p[c];
        __syncthreads();
    }
}

extern "C" void kernel_launch(void* const* d_in, const int* in_sizes, int n_in,
                              void* d_out, int out_size, void* d_ws, size_t ws_size,
                              hipStream_t stream) {
    const float* x    = (const float*)d_in[0];
    const float* w_hx = (const float*)d_in[1];
    const float* w_hh = (const float*)d_in[2];
    const float* b_h  = (const float*)d_in[3];
    const float* w_ph = (const float*)d_in[4];
    const float* b_p  = (const float*)d_in[5];

    void* args[] = { (void*)&x, (void*)&w_hx, (void*)&w_hh, (void*)&b_h };
    hipError_t err = hipLaunchCooperativeKernel((void*)rnn_main, dim3(NWG), dim3(TPB),
                                                args, 0, stream);
    if (err != hipSuccess) {
        rnn_main<<<dim3(NWG), dim3(TPB), 0, stream>>>(x, w_hx, w_hh, b_h);
    }
    proj_kernel<<<dim3(BT), dim3(256), 0, stream>>>(w_ph, b_p, (float*)d_out);
}

// Round 15
// 2740.215 us; speedup vs baseline: 1.0616x; 1.0616x over previous
//
#include <hip/hip_runtime.h>

#define SEQ  512
#define IDIM 256
#define HD   1024
#define BT   256
#define NCLS 10

#define GR    8         // row groups (128 rows each)
#define GB    16        // batch groups (16 cols each)
#define NWG   (GR*GB)   // 128 WGs
#define TPB   512       // 8 waves
#define KKH   32        // h kk-blocks (K=1024)
#define KKX   8         // x kk-blocks (K=256)
#define NSLOT 4         // h slot ring depth
#define SENT  0x7F80    // bf16 +inf: impossible as tanh output

typedef __attribute__((ext_vector_type(8))) short short8;
typedef __attribute__((ext_vector_type(4))) float f32x4;
typedef __attribute__((ext_vector_type(4))) unsigned short us4;
typedef __attribute__((ext_vector_type(4))) int i32x4;

// h slot ring, B-fragment order per col-group; h_t in slot t%4; sentinel
// self-validating data (R12-proven). R15: x-preload via hand-asm loads +
// single vmcnt(2) so publish-store acks NEVER serialize the critical path;
// 4-way split accumulators; lgkm-only phase barrier.
__device__ unsigned short g_h[NSLOT][GB][KKH*64*8];
__device__ float g_hfinal[BT][HD];
__device__ unsigned g_bar, g_done_all;

__device__ __forceinline__ unsigned short f2bf(float f){
    unsigned int u = __builtin_bit_cast(unsigned int, f);
    u += 0x7fffu + ((u >> 16) & 1u);        // round-to-nearest-even
    return (unsigned short)(u >> 16);
}
__device__ __forceinline__ float fast_tanh(float v){
    float e = __expf(2.0f * v);             // exact: tanh = 1 - 2/(e^2v+1)
    return 1.0f - 2.0f / (e + 1.0f);
}
__device__ __forceinline__ void sys_st64(unsigned short* p, unsigned long long v){
    __hip_atomic_store((unsigned long long*)p, v, __ATOMIC_RELAXED, __HIP_MEMORY_SCOPE_SYSTEM);
}
// raw workgroup barrier: LDS-ordered only, NO vmcnt drain
__device__ __forceinline__ void bar_lgkm(){
    asm volatile("s_waitcnt lgkmcnt(0)" ::: "memory");
    __builtin_amdgcn_sched_barrier(0);
    __builtin_amdgcn_s_barrier();
    __builtin_amdgcn_sched_barrier(0);
}

__global__
__attribute__((amdgpu_flat_work_group_size(TPB, TPB), amdgpu_waves_per_eu(2, 2)))
void rnn_main(
    const float* __restrict__ x, const float* __restrict__ w_hx,
    const float* __restrict__ w_hh, const float* __restrict__ b_h)
{
    __shared__ unsigned short sX[8*KKX*64*8];   // 64 KB W_hx A-frags
    __shared__ unsigned short sB2[2][KKH*64*8]; // 2 x 32 KB h slabs

    const int tid = threadIdx.x;
    const int wg  = blockIdx.x;
    const int gbg = wg & (GB-1);
    const int gr  = wg >> 4;
    const int r0  = gr * 128;
    const int b0  = gbg * 16;
    const int l   = tid & 63;
    const int w   = tid >> 6;
    const int rw  = r0 + w*16;
    const int row = rw + (l & 15);
    const int ko  = (l >> 4) << 3;

    // ---- W_hh -> wa, pinned (AGPR residency; R10/R12-proven)
    i32x4 wa[KKH];
    #pragma unroll
    for (int kk = 0; kk < KKH; ++kk){
        f32x4 v0 = *(const f32x4*)(w_hh + (size_t)row*HD + kk*32 + ko);
        f32x4 v1 = *(const f32x4*)(w_hh + (size_t)row*HD + kk*32 + ko + 4);
        us4 lo = { f2bf(v0[0]), f2bf(v0[1]), f2bf(v0[2]), f2bf(v0[3]) };
        us4 hi = { f2bf(v1[0]), f2bf(v1[1]), f2bf(v1[2]), f2bf(v1[3]) };
        unsigned long long a = __builtin_bit_cast(unsigned long long, lo);
        unsigned long long b = __builtin_bit_cast(unsigned long long, hi);
        i32x4 q;
        q[0] = (int)(a & 0xffffffffu); q[1] = (int)(a >> 32);
        q[2] = (int)(b & 0xffffffffu); q[3] = (int)(b >> 32);
        wa[kk] = q;
    }
    #pragma unroll
    for (int kk = 0; kk < KKH; ++kk)
        asm volatile("" : "+v"(wa[kk]));

    // ---- W_hx A-frags -> LDS
    #pragma unroll
    for (int xk = 0; xk < KKX; ++xk){
        f32x4 v0 = *(const f32x4*)(w_hx + (size_t)row*IDIM + xk*32 + ko);
        f32x4 v1 = *(const f32x4*)(w_hx + (size_t)row*IDIM + xk*32 + ko + 4);
        short8 a;
        a[0]=(short)f2bf(v0[0]); a[1]=(short)f2bf(v0[1]);
        a[2]=(short)f2bf(v0[2]); a[3]=(short)f2bf(v0[3]);
        a[4]=(short)f2bf(v1[0]); a[5]=(short)f2bf(v1[1]);
        a[6]=(short)f2bf(v1[2]); a[7]=(short)f2bf(v1[3]);
        *(short8*)&sX[(size_t)((w*KKX + xk)*64 + l)*8] = a;
    }

    const f32x4 bias = *(const f32x4*)(b_h + rw + ((l >> 4) << 2));
    const float* xlane = x + (size_t)(b0 + (l & 15))*(SEQ*IDIM) + ko;

    const int rloc  = w*16 + ((l >> 4) << 2);
    const int kkd   = gr*4 + (rloc >> 5);
    const int lnp   = (l & 15) | (((rloc >> 3) & 3) << 4);
    const int sboff = kkd*512 + lnp*8 + (rloc & 7);
    us4 hw_prev = {0, 0, 0, 0};

    // ---- init ring: slot 0 = zeros (h_0), slots 1..3 = sentinel
    sys_st64(&g_h[0][gbg][sboff], 0ull);
    {
        int sv = SENT;
        #pragma unroll
        for (int s = 1; s < NSLOT; ++s){
            unsigned short* p = &g_h[s][gbg][sboff];
            asm volatile("global_store_short %0, %1, off sc0 sc1" :: "v"(p), "v"(sv) : "memory");
        }
    }
    asm volatile("s_waitcnt vmcnt(0)" ::: "memory");
    __syncthreads();
    if (tid == 0){
        __hip_atomic_fetch_add(&g_bar, 1u, __ATOMIC_ACQ_REL, __HIP_MEMORY_SCOPE_SYSTEM);
        int guard = 0;
        while (__hip_atomic_load(&g_bar, __ATOMIC_ACQUIRE, __HIP_MEMORY_SCOPE_SYSTEM) < NWG
               && ++guard < (1 << 22)) { }
    }
    __syncthreads();

    // ---- x-part prologue for t=0 (compiler-managed; uncritical)
    f32x4 accX = bias;
    #pragma unroll
    for (int xk = 0; xk < KKX; ++xk){
        f32x4 v0 = *(const f32x4*)(xlane + xk*32);
        f32x4 v1 = *(const f32x4*)(xlane + xk*32 + 4);
        short8 bx;
        bx[0]=(short)f2bf(v0[0]); bx[1]=(short)f2bf(v0[1]);
        bx[2]=(short)f2bf(v0[2]); bx[3]=(short)f2bf(v0[3]);
        bx[4]=(short)f2bf(v1[0]); bx[5]=(short)f2bf(v1[1]);
        bx[6]=(short)f2bf(v1[2]); bx[7]=(short)f2bf(v1[3]);
        short8 aw = *(const short8*)&sX[(size_t)((w*KKX + xk)*64 + l)*8];
        accX = __builtin_amdgcn_mfma_f32_16x16x32_bf16(aw, bx, accX, 0, 0, 0);
    }

    for (int t = 0; t < SEQ; ++t){
        const int slot = t & 3;
        const int ns   = (t + 1) & 3;
        const int ps   = (t + 3) & 3;
        unsigned short* sB = &sB2[t & 1][0];

        // ---- phase A: stage slot t (loads only; R12-proven poll)
        *(us4*)&sB[sboff] = hw_prev;
        if (w != gr){
            const unsigned short* base = &g_h[slot][gbg][(size_t)(w*4)*512 + l*8];
            i32x4 v0, v1, v2, v3;
            int guard = 0;
            for (;;){
                asm volatile(
                    "global_load_dwordx4 %0, %4, off sc0 sc1\n\t"
                    "global_load_dwordx4 %1, %4, off offset:1024 sc0 sc1\n\t"
                    "global_load_dwordx4 %2, %4, off offset:2048 sc0 sc1\n\t"
                    "global_load_dwordx4 %3, %4, off offset:3072 sc0 sc1"
                    : "=&v"(v0), "=&v"(v1), "=&v"(v2), "=&v"(v3)
                    : "v"(base));
                asm volatile("s_waitcnt vmcnt(0)" ::: "memory");
                bool ok = ((v0[0] & 0xFFFF) != SENT) && ((v0[2] & 0xFFFF) != SENT)
                       && ((v1[0] & 0xFFFF) != SENT) && ((v1[2] & 0xFFFF) != SENT)
                       && ((v2[0] & 0xFFFF) != SENT) && ((v2[2] & 0xFFFF) != SENT)
                       && ((v3[0] & 0xFFFF) != SENT) && ((v3[2] & 0xFFFF) != SENT);
                if (__all(ok)) break;
                if (++guard > (1 << 18)) break;   // hang safety
            }
            *(i32x4*)&sB[(size_t)(w*4+0)*512 + l*8] = v0;
            *(i32x4*)&sB[(size_t)(w*4+1)*512 + l*8] = v1;
            *(i32x4*)&sB[(size_t)(w*4+2)*512 + l*8] = v2;
            *(i32x4*)&sB[(size_t)(w*4+3)*512 + l*8] = v3;
        }
        bar_lgkm();                               // LDS-only barrier, no ack drain

        // ---- phase B: 4-way split-accumulator MFMA chain (pipelined)
        f32x4 a0 = accX;
        f32x4 a1 = {0.f,0.f,0.f,0.f}, a2 = {0.f,0.f,0.f,0.f}, a3 = {0.f,0.f,0.f,0.f};
        #pragma unroll
        for (int kk = 0; kk < KKH; kk += 4){
            short8 b0 = *(const short8*)&sB[(size_t)((kk+0)*64 + l)*8];
            short8 b1 = *(const short8*)&sB[(size_t)((kk+1)*64 + l)*8];
            short8 b2 = *(const short8*)&sB[(size_t)((kk+2)*64 + l)*8];
            short8 b3 = *(const short8*)&sB[(size_t)((kk+3)*64 + l)*8];
            a0 = __builtin_amdgcn_mfma_f32_16x16x32_bf16(
                     __builtin_bit_cast(short8, wa[kk+0]), b0, a0, 0, 0, 0);
            a1 = __builtin_amdgcn_mfma_f32_16x16x32_bf16(
                     __builtin_bit_cast(short8, wa[kk+1]), b1, a1, 0, 0, 0);
            a2 = __builtin_amdgcn_mfma_f32_16x16x32_bf16(
                     __builtin_bit_cast(short8, wa[kk+2]), b2, a2, 0, 0, 0);
            a3 = __builtin_amdgcn_mfma_f32_16x16x32_bf16(
                     __builtin_bit_cast(short8, wa[kk+3]), b3, a3, 0, 0, 0);
        }
        f32x4 acc = (a0 + a1) + (a2 + a3);
        float h0 = fast_tanh(acc[0]);
        float h1 = fast_tanh(acc[1]);
        float h2 = fast_tanh(acc[2]);
        float h3 = fast_tanh(acc[3]);

        if (t < SEQ-1){
            // ---- issue ALL 16 x(t+1) loads FIRST (hand-asm, no waits)
            const float* xp = xlane + (size_t)(t+1)*IDIM;
            f32x4 xv0[8], xv1[8];
            #pragma unroll
            for (int xk = 0; xk < KKX; ++xk){
                const float* p0 = xp + xk*32;
                const float* p1 = xp + xk*32 + 4;
                asm volatile("global_load_dwordx4 %0, %1, off" : "=&v"(xv0[xk]) : "v"(p0));
                asm volatile("global_load_dwordx4 %0, %1, off" : "=&v"(xv1[xk]) : "v"(p1));
            }
            // ---- publish h_{t+1} + re-arm slot t-1 (fire & forget, AFTER loads)
            us4 hw = { f2bf(h0), f2bf(h1), f2bf(h2), f2bf(h3) };
            unsigned long long hbits = __builtin_bit_cast(unsigned long long, hw);
            unsigned short* hp = &g_h[ns][gbg][sboff];
            asm volatile("global_store_dwordx2 %0, %1, off sc0 sc1" :: "v"(hp), "v"(hbits) : "memory");
            hw_prev = hw;
            {
                int sv = SENT;
                unsigned short* sp = &g_h[ps][gbg][sboff];
                asm volatile("global_store_short %0, %1, off sc0 sc1" :: "v"(sp), "v"(sv) : "memory");
            }
            // ---- wait x data ONLY: the 2 store acks stay in flight
            asm volatile("s_waitcnt vmcnt(2)" ::: "memory");
            __builtin_amdgcn_sched_barrier(0);
            // ---- convert + x-part MFMAs (VALU/LDS only, zero vmem waits)
            f32x4 aX = bias;
            #pragma unroll
            for (int xk = 0; xk < KKX; ++xk){
                f32x4 v0 = xv0[xk], v1 = xv1[xk];
                short8 bx;
                bx[0]=(short)f2bf(v0[0]); bx[1]=(short)f2bf(v0[1]);
                bx[2]=(short)f2bf(v0[2]); bx[3]=(short)f2bf(v0[3]);
                bx[4]=(short)f2bf(v1[0]); bx[5]=(short)f2bf(v1[1]);
                bx[6]=(short)f2bf(v1[2]); bx[7]=(short)f2bf(v1[3]);
                short8 aw = *(const short8*)&sX[(size_t)((w*KKX + xk)*64 + l)*8];
                aX = __builtin_amdgcn_mfma_f32_16x16x32_bf16(aw, bx, aX, 0, 0, 0);
            }
            accX = aX;
        } else {
            f32x4 hf = {h0, h1, h2, h3};
            *(f32x4*)&g_hfinal[b0 + (l & 15)][r0 + rloc] = hf;
        }
    }

    // ---- epilogue: last WG resets the two counters for graph replay
    __syncthreads();
    if (tid == 0){
        unsigned old = __hip_atomic_fetch_add(&g_done_all, 1u,
                           __ATOMIC_ACQ_REL, __HIP_MEMORY_SCOPE_SYSTEM);
        if (old == NWG - 1){
            __hip_atomic_store(&g_bar,      0u, __ATOMIC_RELAXED, __HIP_MEMORY_SCOPE_SYSTEM);
            __hip_atomic_store(&g_done_all, 0u, __ATOMIC_RELAXED, __HIP_MEMORY_SCOPE_SYSTEM);
        }
    }
}

// p = w_ph @ h_final + b_p ; out[b][c]
__global__ __launch_bounds__(256, 1) void proj_kernel(
    const float* __restrict__ w_ph, const float* __restrict__ b_p, float* __restrict__ out)
{
    const int b   = blockIdx.x;
    const int tid = threadIdx.x;
    const int l   = tid & 63;
    const int wv  = tid >> 6;
    __shared__ float red[4];
    f32x4 hv = *(const f32x4*)(&g_hfinal[b][0] + tid*4);
    for (int c = 0; c < NCLS; ++c){
        f32x4 wvv = *(const f32x4*)(w_ph + c*HD + tid*4);
        float s = hv[0]*wvv[0] + hv[1]*wvv[1] + hv[2]*wvv[2] + hv[3]*wvv[3];
        #pragma unroll
        for (int off = 32; off; off >>= 1) s += __shfl_down(s, off, 64);
        if (l == 0) red[wv] = s;
        __syncthreads();
        if (tid == 0) out[b*NCLS + c] = red[0] + red[1] + red[2] + red[3] + b_p[c];
        __syncthreads();
    }
}

extern "C" void kernel_launch(void* const* d_in, const int* in_sizes, int n_in,
                              void* d_out, int out_size, void* d_ws, size_t ws_size,
                              hipStream_t stream) {
    const float* x    = (const float*)d_in[0];
    const float* w_hx = (const float*)d_in[1];
    const float* w_hh = (const float*)d_in[2];
    const float* b_h  = (const float*)d_in[3];
    const float* w_ph = (const float*)d_in[4];
    const float* b_p  = (const float*)d_in[5];

    void* args[] = { (void*)&x, (void*)&w_hx, (void*)&w_hh, (void*)&b_h };
    hipError_t err = hipLaunchCooperativeKernel((void*)rnn_main, dim3(NWG), dim3(TPB),
                                                args, 0, stream);
    if (err != hipSuccess) {
        rnn_main<<<dim3(NWG), dim3(TPB), 0, stream>>>(x, w_hx, w_hh, b_h);
    }
    proj_kernel<<<dim3(BT), dim3(256), 0, stream>>>(w_ph, b_p, (float*)d_out);
}

// Round 16
// 2712.246 us; speedup vs baseline: 1.0725x; 1.0103x over previous
//
#include <hip/hip_runtime.h>

#define SEQ  512
#define IDIM 256
#define HD   1024
#define BT   256
#define NCLS 10

#define GR    8
#define GB    16
#define NWG   (GR*GB)   // 128 WGs
#define TPB   512       // 8 waves
#define KKH   32
#define KKX   8
#define NSLOT 4
#define SENT  0x7F80    // bf16 +inf: impossible as tanh output

typedef __attribute__((ext_vector_type(8))) short short8;
typedef __attribute__((ext_vector_type(4))) float f32x4;
typedef __attribute__((ext_vector_type(4))) unsigned short us4;
typedef __attribute__((ext_vector_type(4))) int i32x4;

// h slot ring (R12 layout/sentinel protocol). R16: ZERO barriers in the
// steady loop -- per-region LDS ready-flags; each wave stages one region
// and consumes regions as they land. Wave skew is bounded at 1 step by the
// publish->stage->consume dependency chain itself.
__device__ unsigned short g_h[NSLOT][GB][KKH*64*8];
__device__ float g_hfinal[BT][HD];
__device__ unsigned g_bar, g_done_all;

__device__ __forceinline__ unsigned short f2bf(float f){
    unsigned int u = __builtin_bit_cast(unsigned int, f);
    u += 0x7fffu + ((u >> 16) & 1u);
    return (unsigned short)(u >> 16);
}
__device__ __forceinline__ float fast_tanh(float v){
    float e = __expf(2.0f * v);
    return 1.0f - 2.0f / (e + 1.0f);
}
__device__ __forceinline__ void sys_st64(unsigned short* p, unsigned long long v){
    __hip_atomic_store((unsigned long long*)p, v, __ATOMIC_RELAXED, __HIP_MEMORY_SCOPE_SYSTEM);
}

__global__
__attribute__((amdgpu_flat_work_group_size(TPB, TPB), amdgpu_waves_per_eu(2, 2)))
void rnn_main(
    const float* __restrict__ x, const float* __restrict__ w_hx,
    const float* __restrict__ w_hh, const float* __restrict__ b_h)
{
    __shared__ unsigned short sX[8*KKX*64*8];   // 64 KB W_hx A-frags
    __shared__ unsigned short sB2[2][KKH*64*8]; // 2 x 32 KB h slabs
    __shared__ int sready[8];                   // per-region ready flags

    const int tid = threadIdx.x;
    const int wg  = blockIdx.x;
    const int gbg = wg & (GB-1);
    const int gr  = wg >> 4;
    const int r0  = gr * 128;
    const int b0  = gbg * 16;
    const int l   = tid & 63;
    const int w   = tid >> 6;
    const int rw  = r0 + w*16;
    const int row = rw + (l & 15);
    const int ko  = (l >> 4) << 3;

    // ---- W_hh -> wa, pinned (AGPR residency; R10/R12-proven)
    i32x4 wa[KKH];
    #pragma unroll
    for (int kk = 0; kk < KKH; ++kk){
        f32x4 v0 = *(const f32x4*)(w_hh + (size_t)row*HD + kk*32 + ko);
        f32x4 v1 = *(const f32x4*)(w_hh + (size_t)row*HD + kk*32 + ko + 4);
        us4 lo = { f2bf(v0[0]), f2bf(v0[1]), f2bf(v0[2]), f2bf(v0[3]) };
        us4 hi = { f2bf(v1[0]), f2bf(v1[1]), f2bf(v1[2]), f2bf(v1[3]) };
        unsigned long long a = __builtin_bit_cast(unsigned long long, lo);
        unsigned long long b = __builtin_bit_cast(unsigned long long, hi);
        i32x4 q;
        q[0] = (int)(a & 0xffffffffu); q[1] = (int)(a >> 32);
        q[2] = (int)(b & 0xffffffffu); q[3] = (int)(b >> 32);
        wa[kk] = q;
    }
    #pragma unroll
    for (int kk = 0; kk < KKH; ++kk)
        asm volatile("" : "+v"(wa[kk]));

    // ---- W_hx A-frags -> LDS
    #pragma unroll
    for (int xk = 0; xk < KKX; ++xk){
        f32x4 v0 = *(const f32x4*)(w_hx + (size_t)row*IDIM + xk*32 + ko);
        f32x4 v1 = *(const f32x4*)(w_hx + (size_t)row*IDIM + xk*32 + ko + 4);
        short8 a;
        a[0]=(short)f2bf(v0[0]); a[1]=(short)f2bf(v0[1]);
        a[2]=(short)f2bf(v0[2]); a[3]=(short)f2bf(v0[3]);
        a[4]=(short)f2bf(v1[0]); a[5]=(short)f2bf(v1[1]);
        a[6]=(short)f2bf(v1[2]); a[7]=(short)f2bf(v1[3]);
        *(short8*)&sX[(size_t)((w*KKX + xk)*64 + l)*8] = a;
    }

    const f32x4 bias = *(const f32x4*)(b_h + rw + ((l >> 4) << 2));
    const float* xlane = x + (size_t)(b0 + (l & 15))*(SEQ*IDIM) + ko;

    const int rloc  = w*16 + ((l >> 4) << 2);
    const int kkd   = gr*4 + (rloc >> 5);
    const int lnp   = (l & 15) | (((rloc >> 3) & 3) << 4);
    const int sboff = kkd*512 + lnp*8 + (rloc & 7);

    // ---- init ring: slot 0 = zeros (h_0), slots 1..3 = sentinel
    sys_st64(&g_h[0][gbg][sboff], 0ull);
    {
        int sv = SENT;
        #pragma unroll
        for (int s = 1; s < NSLOT; ++s){
            unsigned short* p = &g_h[s][gbg][sboff];
            asm volatile("global_store_short %0, %1, off sc0 sc1" :: "v"(p), "v"(sv) : "memory");
        }
    }
    if (tid < 8) sready[tid] = 0;
    asm volatile("s_waitcnt vmcnt(0)" ::: "memory");
    __syncthreads();
    if (tid == 0){
        __hip_atomic_fetch_add(&g_bar, 1u, __ATOMIC_ACQ_REL, __HIP_MEMORY_SCOPE_SYSTEM);
        int guard = 0;
        while (__hip_atomic_load(&g_bar, __ATOMIC_ACQUIRE, __HIP_MEMORY_SCOPE_SYSTEM) < NWG
               && ++guard < (1 << 22)) { }
    }
    __syncthreads();

    auto xpart = [&](const float* xp) -> f32x4 {
        f32x4 a = bias;
        #pragma unroll
        for (int xk = 0; xk < KKX; ++xk){
            f32x4 v0 = *(const f32x4*)(xp + xk*32);
            f32x4 v1 = *(const f32x4*)(xp + xk*32 + 4);
            short8 bx;
            bx[0]=(short)f2bf(v0[0]); bx[1]=(short)f2bf(v0[1]);
            bx[2]=(short)f2bf(v0[2]); bx[3]=(short)f2bf(v0[3]);
            bx[4]=(short)f2bf(v1[0]); bx[5]=(short)f2bf(v1[1]);
            bx[6]=(short)f2bf(v1[2]); bx[7]=(short)f2bf(v1[3]);
            short8 aw = *(const short8*)&sX[(size_t)((w*KKX + xk)*64 + l)*8];
            a = __builtin_amdgcn_mfma_f32_16x16x32_bf16(aw, bx, a, 0, 0, 0);
        }
        return a;
    };
    f32x4 accX = xpart(xlane);

    for (int t = 0; t < SEQ; ++t){
        const int slot = t & 3;
        const int ns   = (t + 1) & 3;
        const int ps   = (t + 3) & 3;
        unsigned short* sB = &sB2[t & 1][0];

        // ---- stage region w of slot t (uniform for all 8 waves), then flag.
        {
            const unsigned short* base = &g_h[slot][gbg][(size_t)(w*4)*512 + l*8];
            i32x4 v0, v1, v2, v3;
            int guard = 0;
            for (;;){
                asm volatile(
                    "global_load_dwordx4 %0, %4, off sc0 sc1\n\t"
                    "global_load_dwordx4 %1, %4, off offset:1024 sc0 sc1\n\t"
                    "global_load_dwordx4 %2, %4, off offset:2048 sc0 sc1\n\t"
                    "global_load_dwordx4 %3, %4, off offset:3072 sc0 sc1"
                    : "=&v"(v0), "=&v"(v1), "=&v"(v2), "=&v"(v3)
                    : "v"(base));
                asm volatile("s_waitcnt vmcnt(0)" ::: "memory");
                bool ok = ((v0[0] & 0xFFFF) != SENT) && ((v0[2] & 0xFFFF) != SENT)
                       && ((v1[0] & 0xFFFF) != SENT) && ((v1[2] & 0xFFFF) != SENT)
                       && ((v2[0] & 0xFFFF) != SENT) && ((v2[2] & 0xFFFF) != SENT)
                       && ((v3[0] & 0xFFFF) != SENT) && ((v3[2] & 0xFFFF) != SENT);
                if (__all(ok)) break;
                if (++guard > (1 << 18)) break;   // hang safety
            }
            *(i32x4*)&sB[(size_t)(w*4+0)*512 + l*8] = v0;
            *(i32x4*)&sB[(size_t)(w*4+1)*512 + l*8] = v1;
            *(i32x4*)&sB[(size_t)(w*4+2)*512 + l*8] = v2;
            *(i32x4*)&sB[(size_t)(w*4+3)*512 + l*8] = v3;
            if (l == 0)
                __hip_atomic_store(&sready[w], t + 1,
                                   __ATOMIC_RELEASE, __HIP_MEMORY_SCOPE_WORKGROUP);
        }

        // ---- consume region-by-region as they land (no barrier)
        f32x4 a0 = accX, a1 = {0.f,0.f,0.f,0.f};
        #pragma unroll
        for (int p = 0; p < 8; ++p){
            if (p != w){                       // own region: just staged
                int guard = 0;
                while (__hip_atomic_load(&sready[p], __ATOMIC_RELAXED,
                                         __HIP_MEMORY_SCOPE_WORKGROUP) < t + 1){
                    if (++guard > (1 << 22)) break;
                }
                __builtin_amdgcn_fence(__ATOMIC_ACQUIRE, "workgroup");
                __builtin_amdgcn_sched_barrier(0);
            }
            short8 b0 = *(const short8*)&sB[(size_t)((p*4+0)*64 + l)*8];
            short8 b1 = *(const short8*)&sB[(size_t)((p*4+1)*64 + l)*8];
            short8 b2 = *(const short8*)&sB[(size_t)((p*4+2)*64 + l)*8];
            short8 b3 = *(const short8*)&sB[(size_t)((p*4+3)*64 + l)*8];
            a0 = __builtin_amdgcn_mfma_f32_16x16x32_bf16(
                     __builtin_bit_cast(short8, wa[p*4+0]), b0, a0, 0, 0, 0);
            a1 = __builtin_amdgcn_mfma_f32_16x16x32_bf16(
                     __builtin_bit_cast(short8, wa[p*4+1]), b1, a1, 0, 0, 0);
            a0 = __builtin_amdgcn_mfma_f32_16x16x32_bf16(
                     __builtin_bit_cast(short8, wa[p*4+2]), b2, a0, 0, 0, 0);
            a1 = __builtin_amdgcn_mfma_f32_16x16x32_bf16(
                     __builtin_bit_cast(short8, wa[p*4+3]), b3, a1, 0, 0, 0);
        }
        f32x4 acc = a0 + a1;
        float h0 = fast_tanh(acc[0]);
        float h1 = fast_tanh(acc[1]);
        float h2 = fast_tanh(acc[2]);
        float h3 = fast_tanh(acc[3]);

        if (t < SEQ-1){
            // publish h_{t+1} + re-arm slot t-1 (both fire & forget).
            // Re-arm safety: we consumed all regions of slot t => all 8 WGs
            // published h_t => all finished staging slot t-1.
            us4 hw = { f2bf(h0), f2bf(h1), f2bf(h2), f2bf(h3) };
            unsigned long long hbits = __builtin_bit_cast(unsigned long long, hw);
            unsigned short* hp = &g_h[ns][gbg][sboff];
            asm volatile("global_store_dwordx2 %0, %1, off sc0 sc1" :: "v"(hp), "v"(hbits) : "memory");
            {
                int sv = SENT;
                unsigned short* sp = &g_h[ps][gbg][sboff];
                asm volatile("global_store_short %0, %1, off sc0 sc1" :: "v"(sp), "v"(sv) : "memory");
            }
            accX = xpart(xlane + (size_t)(t+1)*IDIM);   // overlaps store flight
        } else {
            f32x4 hf = {h0, h1, h2, h3};
            *(f32x4*)&g_hfinal[b0 + (l & 15)][r0 + rloc] = hf;
        }
    }

    // ---- epilogue: last WG resets the two counters for graph replay
    __syncthreads();
    if (tid == 0){
        unsigned old = __hip_atomic_fetch_add(&g_done_all, 1u,
                           __ATOMIC_ACQ_REL, __HIP_MEMORY_SCOPE_SYSTEM);
        if (old == NWG - 1){
            __hip_atomic_store(&g_bar,      0u, __ATOMIC_RELAXED, __HIP_MEMORY_SCOPE_SYSTEM);
            __hip_atomic_store(&g_done_all, 0u, __ATOMIC_RELAXED, __HIP_MEMORY_SCOPE_SYSTEM);
        }
    }
}

// p = w_ph @ h_final + b_p ; out[b][c]
__global__ __launch_bounds__(256, 1) void proj_kernel(
    const float* __restrict__ w_ph, const float* __restrict__ b_p, float* __restrict__ out)
{
    const int b   = blockIdx.x;
    const int tid = threadIdx.x;
    const int l   = tid & 63;
    const int wv  = tid >> 6;
    __shared__ float red[4];
    f32x4 hv = *(const f32x4*)(&g_hfinal[b][0] + tid*4);
    for (int c = 0; c < NCLS; ++c){
        f32x4 wvv = *(const f32x4*)(w_ph + c*HD + tid*4);
        float s = hv[0]*wvv[0] + hv[1]*wvv[1] + hv[2]*wvv[2] + hv[3]*wvv[3];
        #pragma unroll
        for (int off = 32; off; off >>= 1) s += __shfl_down(s, off, 64);
        if (l == 0) red[wv] = s;
        __syncthreads();
        if (tid == 0) out[b*NCLS + c] = red[0] + red[1] + red[2] + red[3] + b_p[c];
        __syncthreads();
    }
}

extern "C" void kernel_launch(void* const* d_in, const int* in_sizes, int n_in,
                              void* d_out, int out_size, void* d_ws, size_t ws_size,
                              hipStream_t stream) {
    const float* x    = (const float*)d_in[0];
    const float* w_hx = (const float*)d_in[1];
    const float* w_hh = (const float*)d_in[2];
    const float* b_h  = (const float*)d_in[3];
    const float* w_ph = (const float*)d_in[4];
    const float* b_p  = (const float*)d_in[5];

    void* args[] = { (void*)&x, (void*)&w_hx, (void*)&w_hh, (void*)&b_h };
    hipError_t err = hipLaunchCooperativeKernel((void*)rnn_main, dim3(NWG), dim3(TPB),
                                                args, 0, stream);
    if (err != hipSuccess) {
        rnn_main<<<dim3(NWG), dim3(TPB), 0, stream>>>(x, w_hx, w_hh, b_h);
    }
    proj_kernel<<<dim3(BT), dim3(256), 0, stream>>>(w_ph, b_p, (float*)d_out);
}

// Round 17
// 2148.112 us; speedup vs baseline: 1.3542x; 1.2626x over previous
//
#include <hip/hip_runtime.h>

#define SEQ  512
#define IDIM 256
#define HD   1024
#define BT   256
#define NCLS 10

#define GR    8
#define GB    16
#define NWG   (GR*GB)   // 128 WGs
#define TPB   512       // 8 waves
#define KKH   32
#define KKX   8
#define NSLOT 4
#define SENT  0x7F80    // bf16 +inf: impossible as tanh output

typedef __attribute__((ext_vector_type(8))) short short8;
typedef __attribute__((ext_vector_type(4))) float f32x4;
typedef __attribute__((ext_vector_type(4))) unsigned short us4;
typedef __attribute__((ext_vector_type(4))) int i32x4;

// h slot ring + sentinel protocol (R12) + barrier-free region flags (R16).
// R17: x deduplicated through a 3-deep LDS frag ring (wave w stages frag
// kk=w once; all waves consume) and x-MFMAs moved AFTER the poll so the
// publish->poll gap is empty and x HBM latency hides under detect.
__device__ unsigned short g_h[NSLOT][GB][KKH*64*8];
__device__ float g_hfinal[BT][HD];
__device__ unsigned g_bar, g_done_all;

__device__ __forceinline__ unsigned short f2bf(float f){
    unsigned int u = __builtin_bit_cast(unsigned int, f);
    u += 0x7fffu + ((u >> 16) & 1u);
    return (unsigned short)(u >> 16);
}
__device__ __forceinline__ float fast_tanh(float v){
    float e = __expf(2.0f * v);
    return 1.0f - 2.0f / (e + 1.0f);
}
__device__ __forceinline__ void sys_st64(unsigned short* p, unsigned long long v){
    __hip_atomic_store((unsigned long long*)p, v, __ATOMIC_RELAXED, __HIP_MEMORY_SCOPE_SYSTEM);
}

__global__
__attribute__((amdgpu_flat_work_group_size(TPB, TPB), amdgpu_waves_per_eu(2, 2)))
void rnn_main(
    const float* __restrict__ x, const float* __restrict__ w_hx,
    const float* __restrict__ w_hh, const float* __restrict__ b_h)
{
    __shared__ unsigned short sX[8*KKX*64*8];   // 64 KB W_hx A-frags
    __shared__ unsigned short sB2[2][KKH*64*8]; // 64 KB h slabs (double)
    __shared__ unsigned short xb[3][KKX*64*8];  // 24 KB x B-frag ring
    __shared__ int sready[8];
    __shared__ int xready[8];

    const int tid = threadIdx.x;
    const int wg  = blockIdx.x;
    const int gbg = wg & (GB-1);
    const int gr  = wg >> 4;
    const int r0  = gr * 128;
    const int b0  = gbg * 16;
    const int l   = tid & 63;
    const int w   = tid >> 6;
    const int rw  = r0 + w*16;
    const int row = rw + (l & 15);
    const int ko  = (l >> 4) << 3;

    // ---- W_hh -> wa, pinned (AGPR residency; R10/R12-proven)
    i32x4 wa[KKH];
    #pragma unroll
    for (int kk = 0; kk < KKH; ++kk){
        f32x4 v0 = *(const f32x4*)(w_hh + (size_t)row*HD + kk*32 + ko);
        f32x4 v1 = *(const f32x4*)(w_hh + (size_t)row*HD + kk*32 + ko + 4);
        us4 lo = { f2bf(v0[0]), f2bf(v0[1]), f2bf(v0[2]), f2bf(v0[3]) };
        us4 hi = { f2bf(v1[0]), f2bf(v1[1]), f2bf(v1[2]), f2bf(v1[3]) };
        unsigned long long a = __builtin_bit_cast(unsigned long long, lo);
        unsigned long long b = __builtin_bit_cast(unsigned long long, hi);
        i32x4 q;
        q[0] = (int)(a & 0xffffffffu); q[1] = (int)(a >> 32);
        q[2] = (int)(b & 0xffffffffu); q[3] = (int)(b >> 32);
        wa[kk] = q;
    }
    #pragma unroll
    for (int kk = 0; kk < KKH; ++kk)
        asm volatile("" : "+v"(wa[kk]));

    // ---- W_hx A-frags -> LDS
    #pragma unroll
    for (int xk = 0; xk < KKX; ++xk){
        f32x4 v0 = *(const f32x4*)(w_hx + (size_t)row*IDIM + xk*32 + ko);
        f32x4 v1 = *(const f32x4*)(w_hx + (size_t)row*IDIM + xk*32 + ko + 4);
        short8 a;
        a[0]=(short)f2bf(v0[0]); a[1]=(short)f2bf(v0[1]);
        a[2]=(short)f2bf(v0[2]); a[3]=(short)f2bf(v0[3]);
        a[4]=(short)f2bf(v1[0]); a[5]=(short)f2bf(v1[1]);
        a[6]=(short)f2bf(v1[2]); a[7]=(short)f2bf(v1[3]);
        *(short8*)&sX[(size_t)((w*KKX + xk)*64 + l)*8] = a;
    }

    const f32x4 bias = *(const f32x4*)(b_h + rw + ((l >> 4) << 2));
    // this wave's x source: frag kk = w (same lane layout as B-frag)
    const float* xwave = x + (size_t)(b0 + (l & 15))*(SEQ*IDIM) + w*32 + ko;

    const int rloc  = w*16 + ((l >> 4) << 2);
    const int kkd   = gr*4 + (rloc >> 5);
    const int lnp   = (l & 15) | (((rloc >> 3) & 3) << 4);
    const int sboff = kkd*512 + lnp*8 + (rloc & 7);

    // ---- init ring: slot 0 = zeros (h_0), slots 1..3 = sentinel
    sys_st64(&g_h[0][gbg][sboff], 0ull);
    {
        int sv = SENT;
        #pragma unroll
        for (int s = 1; s < NSLOT; ++s){
            unsigned short* p = &g_h[s][gbg][sboff];
            asm volatile("global_store_short %0, %1, off sc0 sc1" :: "v"(p), "v"(sv) : "memory");
        }
    }
    // ---- prologue: stage x(0) frag kk=w into xb[0]
    {
        f32x4 v0 = *(const f32x4*)(xwave);
        f32x4 v1 = *(const f32x4*)(xwave + 4);
        short8 bx;
        bx[0]=(short)f2bf(v0[0]); bx[1]=(short)f2bf(v0[1]);
        bx[2]=(short)f2bf(v0[2]); bx[3]=(short)f2bf(v0[3]);
        bx[4]=(short)f2bf(v1[0]); bx[5]=(short)f2bf(v1[1]);
        bx[6]=(short)f2bf(v1[2]); bx[7]=(short)f2bf(v1[3]);
        *(short8*)&xb[0][(size_t)(w*64 + l)*8] = bx;
    }
    if (tid < 8){ sready[tid] = 0; xready[tid] = 1; }
    asm volatile("s_waitcnt vmcnt(0)" ::: "memory");
    __syncthreads();
    if (tid == 0){
        __hip_atomic_fetch_add(&g_bar, 1u, __ATOMIC_ACQ_REL, __HIP_MEMORY_SCOPE_SYSTEM);
        int guard = 0;
        while (__hip_atomic_load(&g_bar, __ATOMIC_ACQUIRE, __HIP_MEMORY_SCOPE_SYSTEM) < NWG
               && ++guard < (1 << 22)) { }
    }
    __syncthreads();

    int cur = 0;                                  // t % 3
    for (int t = 0; t < SEQ; ++t){
        const int slot = t & 3;
        const int ns   = (t + 1) & 3;
        const int ps   = (t + 3) & 3;
        const int nxt  = (cur == 2) ? 0 : cur + 1;  // (t+1) % 3
        unsigned short* sB = &sB2[t & 1][0];
        const bool do_x = (t + 1 < SEQ);

        // ---- (a) issue x(t+1) loads: fire & forget, retire under the poll
        f32x4 xv0, xv1;
        if (do_x){
            const float* xp = xwave + (size_t)(t+1)*IDIM;
            asm volatile(
                "global_load_dwordx4 %0, %2, off\n\t"
                "global_load_dwordx4 %1, %2, off offset:16"
                : "=&v"(xv0), "=&v"(xv1) : "v"(xp));
        }

        // ---- (b) poll region w of slot t (R16-proven; vmcnt(0) covers x too)
        {
            const unsigned short* base = &g_h[slot][gbg][(size_t)(w*4)*512 + l*8];
            i32x4 v0, v1, v2, v3;
            int guard = 0;
            for (;;){
                asm volatile(
                    "global_load_dwordx4 %0, %4, off sc0 sc1\n\t"
                    "global_load_dwordx4 %1, %4, off offset:1024 sc0 sc1\n\t"
                    "global_load_dwordx4 %2, %4, off offset:2048 sc0 sc1\n\t"
                    "global_load_dwordx4 %3, %4, off offset:3072 sc0 sc1"
                    : "=&v"(v0), "=&v"(v1), "=&v"(v2), "=&v"(v3)
                    : "v"(base));
                asm volatile("s_waitcnt vmcnt(0)" ::: "memory");
                bool ok = ((v0[0] & 0xFFFF) != SENT) && ((v0[2] & 0xFFFF) != SENT)
                       && ((v1[0] & 0xFFFF) != SENT) && ((v1[2] & 0xFFFF) != SENT)
                       && ((v2[0] & 0xFFFF) != SENT) && ((v2[2] & 0xFFFF) != SENT)
                       && ((v3[0] & 0xFFFF) != SENT) && ((v3[2] & 0xFFFF) != SENT);
                if (__all(ok)) break;
                if (++guard > (1 << 18)) break;   // hang safety
            }
            *(i32x4*)&sB[(size_t)(w*4+0)*512 + l*8] = v0;
            *(i32x4*)&sB[(size_t)(w*4+1)*512 + l*8] = v1;
            *(i32x4*)&sB[(size_t)(w*4+2)*512 + l*8] = v2;
            *(i32x4*)&sB[(size_t)(w*4+3)*512 + l*8] = v3;
            if (l == 0)
                __hip_atomic_store(&sready[w], t + 1,
                                   __ATOMIC_RELEASE, __HIP_MEMORY_SCOPE_WORKGROUP);
        }

        // ---- (c) x(t+1): cvt + LDS write + flag (data arrived during poll)
        if (do_x){
            short8 bx;
            bx[0]=(short)f2bf(xv0[0]); bx[1]=(short)f2bf(xv0[1]);
            bx[2]=(short)f2bf(xv0[2]); bx[3]=(short)f2bf(xv0[3]);
            bx[4]=(short)f2bf(xv1[0]); bx[5]=(short)f2bf(xv1[1]);
            bx[6]=(short)f2bf(xv1[2]); bx[7]=(short)f2bf(xv1[3]);
            *(short8*)&xb[nxt][(size_t)(w*64 + l)*8] = bx;
            if (l == 0)
                __hip_atomic_store(&xready[w], t + 2,
                                   __ATOMIC_RELEASE, __HIP_MEMORY_SCOPE_WORKGROUP);
        }

        // ---- (d) x-part MFMAs for step t from xb[cur]
        f32x4 aX = bias;
        #pragma unroll
        for (int p = 0; p < KKX; ++p){
            if (p != w){
                int guard = 0;
                while (__hip_atomic_load(&xready[p], __ATOMIC_RELAXED,
                                         __HIP_MEMORY_SCOPE_WORKGROUP) < t + 1){
                    if (++guard > (1 << 22)) break;
                }
                __builtin_amdgcn_fence(__ATOMIC_ACQUIRE, "workgroup");
                __builtin_amdgcn_sched_barrier(0);
            }
            short8 bx = *(const short8*)&xb[cur][(size_t)(p*64 + l)*8];
            short8 aw = *(const short8*)&sX[(size_t)((w*KKX + p)*64 + l)*8];
            aX = __builtin_amdgcn_mfma_f32_16x16x32_bf16(aw, bx, aX, 0, 0, 0);
        }

        // ---- (e) h-part: consume regions as they land (R16-proven)
        f32x4 a0 = aX, a1 = {0.f,0.f,0.f,0.f};
        #pragma unroll
        for (int p = 0; p < 8; ++p){
            if (p != w){
                int guard = 0;
                while (__hip_atomic_load(&sready[p], __ATOMIC_RELAXED,
                                         __HIP_MEMORY_SCOPE_WORKGROUP) < t + 1){
                    if (++guard > (1 << 22)) break;
                }
                __builtin_amdgcn_fence(__ATOMIC_ACQUIRE, "workgroup");
                __builtin_amdgcn_sched_barrier(0);
            }
            short8 b0 = *(const short8*)&sB[(size_t)((p*4+0)*64 + l)*8];
            short8 b1 = *(const short8*)&sB[(size_t)((p*4+1)*64 + l)*8];
            short8 b2 = *(const short8*)&sB[(size_t)((p*4+2)*64 + l)*8];
            short8 b3 = *(const short8*)&sB[(size_t)((p*4+3)*64 + l)*8];
            a0 = __builtin_amdgcn_mfma_f32_16x16x32_bf16(
                     __builtin_bit_cast(short8, wa[p*4+0]), b0, a0, 0, 0, 0);
            a1 = __builtin_amdgcn_mfma_f32_16x16x32_bf16(
                     __builtin_bit_cast(short8, wa[p*4+1]), b1, a1, 0, 0, 0);
            a0 = __builtin_amdgcn_mfma_f32_16x16x32_bf16(
                     __builtin_bit_cast(short8, wa[p*4+2]), b2, a0, 0, 0, 0);
            a1 = __builtin_amdgcn_mfma_f32_16x16x32_bf16(
                     __builtin_bit_cast(short8, wa[p*4+3]), b3, a1, 0, 0, 0);
        }
        f32x4 acc = a0 + a1;
        float h0 = fast_tanh(acc[0]);
        float h1 = fast_tanh(acc[1]);
        float h2 = fast_tanh(acc[2]);
        float h3 = fast_tanh(acc[3]);

        // ---- (f) publish h_{t+1} + re-arm slot t-1 (fire & forget)
        if (t < SEQ-1){
            us4 hw = { f2bf(h0), f2bf(h1), f2bf(h2), f2bf(h3) };
            unsigned long long hbits = __builtin_bit_cast(unsigned long long, hw);
            unsigned short* hp = &g_h[ns][gbg][sboff];
            asm volatile("global_store_dwordx2 %0, %1, off sc0 sc1" :: "v"(hp), "v"(hbits) : "memory");
            {
                int sv = SENT;
                unsigned short* sp = &g_h[ps][gbg][sboff];
                asm volatile("global_store_short %0, %1, off sc0 sc1" :: "v"(sp), "v"(sv) : "memory");
            }
        } else {
            f32x4 hf = {h0, h1, h2, h3};
            *(f32x4*)&g_hfinal[b0 + (l & 15)][r0 + rloc] = hf;
        }
        cur = nxt;
    }

    // ---- epilogue: last WG resets the two counters for graph replay
    __syncthreads();
    if (tid == 0){
        unsigned old = __hip_atomic_fetch_add(&g_done_all, 1u,
                           __ATOMIC_ACQ_REL, __HIP_MEMORY_SCOPE_SYSTEM);
        if (old == NWG - 1){
            __hip_atomic_store(&g_bar,      0u, __ATOMIC_RELAXED, __HIP_MEMORY_SCOPE_SYSTEM);
            __hip_atomic_store(&g_done_all, 0u, __ATOMIC_RELAXED, __HIP_MEMORY_SCOPE_SYSTEM);
        }
    }
}

// p = w_ph @ h_final + b_p ; out[b][c]
__global__ __launch_bounds__(256, 1) void proj_kernel(
    const float* __restrict__ w_ph, const float* __restrict__ b_p, float* __restrict__ out)
{
    const int b   = blockIdx.x;
    const int tid = threadIdx.x;
    const int l   = tid & 63;
    const int wv  = tid >> 6;
    __shared__ float red[4];
    f32x4 hv = *(const f32x4*)(&g_hfinal[b][0] + tid*4);
    for (int c = 0; c < NCLS; ++c){
        f32x4 wvv = *(const f32x4*)(w_ph + c*HD + tid*4);
        float s = hv[0]*wvv[0] + hv[1]*wvv[1] + hv[2]*wvv[2] + hv[3]*wvv[3];
        #pragma unroll
        for (int off = 32; off; off >>= 1) s += __shfl_down(s, off, 64);
        if (l == 0) red[wv] = s;
        __syncthreads();
        if (tid == 0) out[b*NCLS + c] = red[0] + red[1] + red[2] + red[3] + b_p[c];
        __syncthreads();
    }
}

extern "C" void kernel_launch(void* const* d_in, const int* in_sizes, int n_in,
                              void* d_out, int out_size, void* d_ws, size_t ws_size,
                              hipStream_t stream) {
    const float* x    = (const float*)d_in[0];
    const float* w_hx = (const float*)d_in[1];
    const float* w_hh = (const float*)d_in[2];
    const float* b_h  = (const float*)d_in[3];
    const float* w_ph = (const float*)d_in[4];
    const float* b_p  = (const float*)d_in[5];

    void* args[] = { (void*)&x, (void*)&w_hx, (void*)&w_hh, (void*)&b_h };
    hipError_t err = hipLaunchCooperativeKernel((void*)rnn_main, dim3(NWG), dim3(TPB),
                                                args, 0, stream);
    if (err != hipSuccess) {
        rnn_main<<<dim3(NWG), dim3(TPB), 0, stream>>>(x, w_hx, w_hh, b_h);
    }
    proj_kernel<<<dim3(BT), dim3(256), 0, stream>>>(w_ph, b_p, (float*)d_out);
}

// Round 18
// 2116.069 us; speedup vs baseline: 1.3747x; 1.0151x over previous
//
#include <hip/hip_runtime.h>

#define SEQ  512
#define IDIM 256
#define HD   1024
#define BT   256
#define NCLS 10

#define GR    8
#define GB    16
#define NWG   (GR*GB)   // 128 WGs
#define TPB   512       // 8 waves
#define KKH   32
#define KKX   8
#define NSLOT 4
#define SENT  0x7F80    // bf16 +inf: impossible as tanh output

typedef __attribute__((ext_vector_type(8))) short short8;
typedef __attribute__((ext_vector_type(4))) float f32x4;
typedef __attribute__((ext_vector_type(4))) unsigned short us4;
typedef __attribute__((ext_vector_type(4))) int i32x4;

// h slot ring + sentinel (R12) + barrier-free region flags (R16) + x dedup
// through LDS ring (R17). R18: x prefetch distance 2 with poll-first issue
// order + vmcnt(2), so x loads NEVER retire on the critical path; x staging
// moved after publish.
__device__ unsigned short g_h[NSLOT][GB][KKH*64*8];
__device__ float g_hfinal[BT][HD];
__device__ unsigned g_bar, g_done_all;

__device__ __forceinline__ unsigned short f2bf(float f){
    unsigned int u = __builtin_bit_cast(unsigned int, f);
    u += 0x7fffu + ((u >> 16) & 1u);
    return (unsigned short)(u >> 16);
}
__device__ __forceinline__ float fast_tanh(float v){
    float e = __expf(2.0f * v);
    return 1.0f - 2.0f / (e + 1.0f);
}
__device__ __forceinline__ void sys_st64(unsigned short* p, unsigned long long v){
    __hip_atomic_store((unsigned long long*)p, v, __ATOMIC_RELAXED, __HIP_MEMORY_SCOPE_SYSTEM);
}

__global__
__attribute__((amdgpu_flat_work_group_size(TPB, TPB), amdgpu_waves_per_eu(2, 2)))
void rnn_main(
    const float* __restrict__ x, const float* __restrict__ w_hx,
    const float* __restrict__ w_hh, const float* __restrict__ b_h)
{
    __shared__ unsigned short sX[8*KKX*64*8];   // 64 KB W_hx A-frags
    __shared__ unsigned short sB2[2][KKH*64*8]; // 64 KB h slabs (double)
    __shared__ unsigned short xb[3][KKX*64*8];  // 24 KB x B-frag ring
    __shared__ int sready[8];
    __shared__ int xready[8];

    const int tid = threadIdx.x;
    const int wg  = blockIdx.x;
    const int gbg = wg & (GB-1);
    const int gr  = wg >> 4;
    const int r0  = gr * 128;
    const int b0  = gbg * 16;
    const int l   = tid & 63;
    const int w   = tid >> 6;
    const int rw  = r0 + w*16;
    const int row = rw + (l & 15);
    const int ko  = (l >> 4) << 3;

    // ---- W_hh -> wa, pinned (AGPR residency; R10/R12-proven)
    i32x4 wa[KKH];
    #pragma unroll
    for (int kk = 0; kk < KKH; ++kk){
        f32x4 v0 = *(const f32x4*)(w_hh + (size_t)row*HD + kk*32 + ko);
        f32x4 v1 = *(const f32x4*)(w_hh + (size_t)row*HD + kk*32 + ko + 4);
        us4 lo = { f2bf(v0[0]), f2bf(v0[1]), f2bf(v0[2]), f2bf(v0[3]) };
        us4 hi = { f2bf(v1[0]), f2bf(v1[1]), f2bf(v1[2]), f2bf(v1[3]) };
        unsigned long long a = __builtin_bit_cast(unsigned long long, lo);
        unsigned long long b = __builtin_bit_cast(unsigned long long, hi);
        i32x4 q;
        q[0] = (int)(a & 0xffffffffu); q[1] = (int)(a >> 32);
        q[2] = (int)(b & 0xffffffffu); q[3] = (int)(b >> 32);
        wa[kk] = q;
    }
    #pragma unroll
    for (int kk = 0; kk < KKH; ++kk)
        asm volatile("" : "+v"(wa[kk]));

    // ---- W_hx A-frags -> LDS
    #pragma unroll
    for (int xk = 0; xk < KKX; ++xk){
        f32x4 v0 = *(const f32x4*)(w_hx + (size_t)row*IDIM + xk*32 + ko);
        f32x4 v1 = *(const f32x4*)(w_hx + (size_t)row*IDIM + xk*32 + ko + 4);
        short8 a;
        a[0]=(short)f2bf(v0[0]); a[1]=(short)f2bf(v0[1]);
        a[2]=(short)f2bf(v0[2]); a[3]=(short)f2bf(v0[3]);
        a[4]=(short)f2bf(v1[0]); a[5]=(short)f2bf(v1[1]);
        a[6]=(short)f2bf(v1[2]); a[7]=(short)f2bf(v1[3]);
        *(short8*)&sX[(size_t)((w*KKX + xk)*64 + l)*8] = a;
    }

    const f32x4 bias = *(const f32x4*)(b_h + rw + ((l >> 4) << 2));
    const float* xwave = x + (size_t)(b0 + (l & 15))*(SEQ*IDIM) + w*32 + ko;

    const int rloc  = w*16 + ((l >> 4) << 2);
    const int kkd   = gr*4 + (rloc >> 5);
    const int lnp   = (l & 15) | (((rloc >> 3) & 3) << 4);
    const int sboff = kkd*512 + lnp*8 + (rloc & 7);

    // ---- init ring: slot 0 = zeros (h_0), slots 1..3 = sentinel
    sys_st64(&g_h[0][gbg][sboff], 0ull);
    {
        int sv = SENT;
        #pragma unroll
        for (int s = 1; s < NSLOT; ++s){
            unsigned short* p = &g_h[s][gbg][sboff];
            asm volatile("global_store_short %0, %1, off sc0 sc1" :: "v"(p), "v"(sv) : "memory");
        }
    }
    // ---- prologue: stage x(0) into xb[0]; preload x(1) into regs
    {
        f32x4 v0 = *(const f32x4*)(xwave);
        f32x4 v1 = *(const f32x4*)(xwave + 4);
        short8 bx;
        bx[0]=(short)f2bf(v0[0]); bx[1]=(short)f2bf(v0[1]);
        bx[2]=(short)f2bf(v0[2]); bx[3]=(short)f2bf(v0[3]);
        bx[4]=(short)f2bf(v1[0]); bx[5]=(short)f2bf(v1[1]);
        bx[6]=(short)f2bf(v1[2]); bx[7]=(short)f2bf(v1[3]);
        *(short8*)&xb[0][(size_t)(w*64 + l)*8] = bx;
    }
    f32x4 xr0 = *(const f32x4*)(xwave + IDIM);      // x(1), consumed at t=0's (c)
    f32x4 xr1 = *(const f32x4*)(xwave + IDIM + 4);
    if (tid < 8){ sready[tid] = 0; xready[tid] = 1; }
    asm volatile("s_waitcnt vmcnt(0)" ::: "memory");
    __syncthreads();
    if (tid == 0){
        __hip_atomic_fetch_add(&g_bar, 1u, __ATOMIC_ACQ_REL, __HIP_MEMORY_SCOPE_SYSTEM);
        int guard = 0;
        while (__hip_atomic_load(&g_bar, __ATOMIC_ACQUIRE, __HIP_MEMORY_SCOPE_SYSTEM) < NWG
               && ++guard < (1 << 22)) { }
    }
    __syncthreads();

    int cur = 0;                                  // t % 3
    for (int t = 0; t < SEQ; ++t){
        const int slot = t & 3;
        const int ns   = (t + 1) & 3;
        const int ps   = (t + 3) & 3;
        const int nxt  = (cur == 2) ? 0 : cur + 1;
        unsigned short* sB = &sB2[t & 1][0];
        const bool pf_x = (t + 2 < SEQ);          // prefetch x(t+2) this step

        // ---- (b) poll region w of slot t. First iteration: poll loads
        // issued FIRST, then x(t+2) loads, then vmcnt(2) -> poll data ready,
        // x (newest 2) stays in flight. Retries use vmcnt(0) (waiting anyway).
        f32x4 nx0, nx1;
        {
            const unsigned short* base = &g_h[slot][gbg][(size_t)(w*4)*512 + l*8];
            i32x4 v0, v1, v2, v3;
            // first iteration
            asm volatile(
                "global_load_dwordx4 %0, %4, off sc0 sc1\n\t"
                "global_load_dwordx4 %1, %4, off offset:1024 sc0 sc1\n\t"
                "global_load_dwordx4 %2, %4, off offset:2048 sc0 sc1\n\t"
                "global_load_dwordx4 %3, %4, off offset:3072 sc0 sc1"
                : "=&v"(v0), "=&v"(v1), "=&v"(v2), "=&v"(v3)
                : "v"(base));
            if (pf_x){
                const float* xp = xwave + (size_t)(t+2)*IDIM;
                asm volatile(
                    "global_load_dwordx4 %0, %2, off\n\t"
                    "global_load_dwordx4 %1, %2, off offset:16"
                    : "=&v"(nx0), "=&v"(nx1) : "v"(xp));
                asm volatile("s_waitcnt vmcnt(2)" ::: "memory");
            } else {
                asm volatile("s_waitcnt vmcnt(0)" ::: "memory");
            }
            bool ok = ((v0[0] & 0xFFFF) != SENT) && ((v0[2] & 0xFFFF) != SENT)
                   && ((v1[0] & 0xFFFF) != SENT) && ((v1[2] & 0xFFFF) != SENT)
                   && ((v2[0] & 0xFFFF) != SENT) && ((v2[2] & 0xFFFF) != SENT)
                   && ((v3[0] & 0xFFFF) != SENT) && ((v3[2] & 0xFFFF) != SENT);
            int guard = 0;
            while (!__all(ok)){
                asm volatile(
                    "global_load_dwordx4 %0, %4, off sc0 sc1\n\t"
                    "global_load_dwordx4 %1, %4, off offset:1024 sc0 sc1\n\t"
                    "global_load_dwordx4 %2, %4, off offset:2048 sc0 sc1\n\t"
                    "global_load_dwordx4 %3, %4, off offset:3072 sc0 sc1"
                    : "=&v"(v0), "=&v"(v1), "=&v"(v2), "=&v"(v3)
                    : "v"(base));
                asm volatile("s_waitcnt vmcnt(0)" ::: "memory");
                ok = ((v0[0] & 0xFFFF) != SENT) && ((v0[2] & 0xFFFF) != SENT)
                  && ((v1[0] & 0xFFFF) != SENT) && ((v1[2] & 0xFFFF) != SENT)
                  && ((v2[0] & 0xFFFF) != SENT) && ((v2[2] & 0xFFFF) != SENT)
                  && ((v3[0] & 0xFFFF) != SENT) && ((v3[2] & 0xFFFF) != SENT);
                if (++guard > (1 << 18)) break;   // hang safety
            }
            *(i32x4*)&sB[(size_t)(w*4+0)*512 + l*8] = v0;
            *(i32x4*)&sB[(size_t)(w*4+1)*512 + l*8] = v1;
            *(i32x4*)&sB[(size_t)(w*4+2)*512 + l*8] = v2;
            *(i32x4*)&sB[(size_t)(w*4+3)*512 + l*8] = v3;
            if (l == 0)
                __hip_atomic_store(&sready[w], t + 1,
                                   __ATOMIC_RELEASE, __HIP_MEMORY_SCOPE_WORKGROUP);
        }

        // ---- (d) x-part MFMAs for step t from xb[cur] (staged at t-1)
        f32x4 aX = bias;
        #pragma unroll
        for (int p = 0; p < KKX; ++p){
            if (p != w){
                int guard = 0;
                while (__hip_atomic_load(&xready[p], __ATOMIC_RELAXED,
                                         __HIP_MEMORY_SCOPE_WORKGROUP) < t + 1){
                    if (++guard > (1 << 22)) break;
                }
                __builtin_amdgcn_fence(__ATOMIC_ACQUIRE, "workgroup");
                __builtin_amdgcn_sched_barrier(0);
            }
            short8 bx = *(const short8*)&xb[cur][(size_t)(p*64 + l)*8];
            short8 aw = *(const short8*)&sX[(size_t)((w*KKX + p)*64 + l)*8];
            aX = __builtin_amdgcn_mfma_f32_16x16x32_bf16(aw, bx, aX, 0, 0, 0);
        }

        // ---- (e) h-part: consume regions as they land (R16-proven)
        f32x4 a0 = aX, a1 = {0.f,0.f,0.f,0.f};
        #pragma unroll
        for (int p = 0; p < 8; ++p){
            if (p != w){
                int guard = 0;
                while (__hip_atomic_load(&sready[p], __ATOMIC_RELAXED,
                                         __HIP_MEMORY_SCOPE_WORKGROUP) < t + 1){
                    if (++guard > (1 << 22)) break;
                }
                __builtin_amdgcn_fence(__ATOMIC_ACQUIRE, "workgroup");
                __builtin_amdgcn_sched_barrier(0);
            }
            short8 b0 = *(const short8*)&sB[(size_t)((p*4+0)*64 + l)*8];
            short8 b1 = *(const short8*)&sB[(size_t)((p*4+1)*64 + l)*8];
            short8 b2 = *(const short8*)&sB[(size_t)((p*4+2)*64 + l)*8];
            short8 b3 = *(const short8*)&sB[(size_t)((p*4+3)*64 + l)*8];
            a0 = __builtin_amdgcn_mfma_f32_16x16x32_bf16(
                     __builtin_bit_cast(short8, wa[p*4+0]), b0, a0, 0, 0, 0);
            a1 = __builtin_amdgcn_mfma_f32_16x16x32_bf16(
                     __builtin_bit_cast(short8, wa[p*4+1]), b1, a1, 0, 0, 0);
            a0 = __builtin_amdgcn_mfma_f32_16x16x32_bf16(
                     __builtin_bit_cast(short8, wa[p*4+2]), b2, a0, 0, 0, 0);
            a1 = __builtin_amdgcn_mfma_f32_16x16x32_bf16(
                     __builtin_bit_cast(short8, wa[p*4+3]), b3, a1, 0, 0, 0);
        }
        f32x4 acc = a0 + a1;
        float h0 = fast_tanh(acc[0]);
        float h1 = fast_tanh(acc[1]);
        float h2 = fast_tanh(acc[2]);
        float h3 = fast_tanh(acc[3]);

        // ---- (f) publish h_{t+1} + re-arm slot t-1 (fire & forget)
        if (t < SEQ-1){
            us4 hw = { f2bf(h0), f2bf(h1), f2bf(h2), f2bf(h3) };
            unsigned long long hbits = __builtin_bit_cast(unsigned long long, hw);
            unsigned short* hp = &g_h[ns][gbg][sboff];
            asm volatile("global_store_dwordx2 %0, %1, off sc0 sc1" :: "v"(hp), "v"(hbits) : "memory");
            {
                int sv = SENT;
                unsigned short* sp = &g_h[ps][gbg][sboff];
                asm volatile("global_store_short %0, %1, off sc0 sc1" :: "v"(sp), "v"(sv) : "memory");
            }
        } else {
            f32x4 hf = {h0, h1, h2, h3};
            *(f32x4*)&g_hfinal[b0 + (l & 15)][r0 + rloc] = hf;
        }

        // ---- (c) POST-publish: stage x(t+1) from regs (loaded at t-1,
        // provably retired), then roll prefetch regs.
        if (t + 1 < SEQ){
            short8 bx;
            bx[0]=(short)f2bf(xr0[0]); bx[1]=(short)f2bf(xr0[1]);
            bx[2]=(short)f2bf(xr0[2]); bx[3]=(short)f2bf(xr0[3]);
            bx[4]=(short)f2bf(xr1[0]); bx[5]=(short)f2bf(xr1[1]);
            bx[6]=(short)f2bf(xr1[2]); bx[7]=(short)f2bf(xr1[3]);
            *(short8*)&xb[nxt][(size_t)(w*64 + l)*8] = bx;
            if (l == 0)
                __hip_atomic_store(&xready[w], t + 2,
                                   __ATOMIC_RELEASE, __HIP_MEMORY_SCOPE_WORKGROUP);
            if (pf_x){ xr0 = nx0; xr1 = nx1; }    // x(t+2) regs for next (c)
        }
        cur = nxt;
    }

    // ---- epilogue: last WG resets the two counters for graph replay
    __syncthreads();
    if (tid == 0){
        unsigned old = __hip_atomic_fetch_add(&g_done_all, 1u,
                           __ATOMIC_ACQ_REL, __HIP_MEMORY_SCOPE_SYSTEM);
        if (old == NWG - 1){
            __hip_atomic_store(&g_bar,      0u, __ATOMIC_RELAXED, __HIP_MEMORY_SCOPE_SYSTEM);
            __hip_atomic_store(&g_done_all, 0u, __ATOMIC_RELAXED, __HIP_MEMORY_SCOPE_SYSTEM);
        }
    }
}

// p = w_ph @ h_final + b_p ; out[b][c]
__global__ __launch_bounds__(256, 1) void proj_kernel(
    const float* __restrict__ w_ph, const float* __restrict__ b_p, float* __restrict__ out)
{
    const int b   = blockIdx.x;
    const int tid = threadIdx.x;
    const int l   = tid & 63;
    const int wv  = tid >> 6;
    __shared__ float red[4];
    f32x4 hv = *(const f32x4*)(&g_hfinal[b][0] + tid*4);
    for (int c = 0; c < NCLS; ++c){
        f32x4 wvv = *(const f32x4*)(w_ph + c*HD + tid*4);
        float s = hv[0]*wvv[0] + hv[1]*wvv[1] + hv[2]*wvv[2] + hv[3]*wvv[3];
        #pragma unroll
        for (int off = 32; off; off >>= 1) s += __shfl_down(s, off, 64);
        if (l == 0) red[wv] = s;
        __syncthreads();
        if (tid == 0) out[b*NCLS + c] = red[0] + red[1] + red[2] + red[3] + b_p[c];
        __syncthreads();
    }
}

extern "C" void kernel_launch(void* const* d_in, const int* in_sizes, int n_in,
                              void* d_out, int out_size, void* d_ws, size_t ws_size,
                              hipStream_t stream) {
    const float* x    = (const float*)d_in[0];
    const float* w_hx = (const float*)d_in[1];
    const float* w_hh = (const float*)d_in[2];
    const float* b_h  = (const float*)d_in[3];
    const float* w_ph = (const float*)d_in[4];
    const float* b_p  = (const float*)d_in[5];

    void* args[] = { (void*)&x, (void*)&w_hx, (void*)&w_hh, (void*)&b_h };
    hipError_t err = hipLaunchCooperativeKernel((void*)rnn_main, dim3(NWG), dim3(TPB),
                                                args, 0, stream);
    if (err != hipSuccess) {
        rnn_main<<<dim3(NWG), dim3(TPB), 0, stream>>>(x, w_hx, w_hh, b_h);
    }
    proj_kernel<<<dim3(BT), dim3(256), 0, stream>>>(w_ph, b_p, (float*)d_out);
}